// Round 10
// baseline (316.303 us; speedup 1.0000x reference)
//
#include <hip/hip_runtime.h>
#include <hip/hip_cooperative_groups.h>
#include <math.h>

namespace cg = cooperative_groups;

namespace {
constexpr int B_ = 4, K_ = 8, W_ = 1024;
constexpr int N_ = 512 * 1024;          // pixels per image
constexpr int M_ = 256;                 // err histogram bins over [0,2]
constexpr int MP_ = M_ + 1;             // padded LDS row
constexpr int BK_ = B_ * K_;
constexpr int KM_ = K_ * M_;            // 2048 bins per hist-unit partial

constexpr int US_ = 1024, SBPB_ = 256, SCH_ = 2048;   // stats units
constexpr int UH_ = 1024, HBPB_ = 256, HCH_ = 2048;   // hist units
constexpr int NSTAT = 41;               // k*5+{cnt,xm,ym,s,s2}, [40]=bg
constexpr int SLICES_ = 32, PERS_ = 8;  // reduce: 32 slices x 8 partials per (b,k)

// workspace layout (bytes)
constexpr size_t PART_SZ  = (size_t)UH_ * KM_ * 4;               // 8 MB
constexpr size_t SFG_B    = PART_SZ;                             // 32 KB
constexpr size_t PSTAT_B  = SFG_B + (size_t)BK_ * HBPB_ * 4;     // 168 KB
constexpr size_t RED_B    = PSTAT_B + (size_t)B_ * NSTAT * SBPB_ * 4;  // 1 MB
constexpr size_t WSF_B    = RED_B + (size_t)BK_ * SLICES_ * M_ * 4;

constexpr int CNT_OFF = 0, OBJF_OFF = 32;   // wsf float offsets
}

__device__ __forceinline__ float fsigmoid_(float x) { return 1.0f / (1.0f + __expf(-x)); }
__device__ __forceinline__ float ftanh_(float x) { return 1.0f - 2.0f / (__expf(2.0f * x) + 1.0f); }

// Single cooperative kernel; phases separated by grid.sync(). All phase loops
// are grid-stride so any co-resident grid size (<=1024) is correct.
__global__ __launch_bounds__(256) void fused_kernel(
    const float* __restrict__ pred, const int* __restrict__ inst,
    const int* __restrict__ lab, float* __restrict__ pstat,
    unsigned int* __restrict__ partial, float* __restrict__ sfgpart,
    unsigned int* __restrict__ red, float* __restrict__ wsf,
    float* __restrict__ out)
{
    cg::grid_group gg = cg::this_grid();
    int tid = threadIdx.x;

    // static LDS, max-phase total ~13 KB (no occupancy constraint at 160 KB/CU)
    __shared__ float ws1[4 * 48];            // phase 1: per-wave stat accumulators
    __shared__ float sq[NSTAT][4];           // phase 2 prologue
    __shared__ float ssum[NSTAT];
    __shared__ float prm[K_][4];
    __shared__ float svar[K_];
    __shared__ int spres[K_];
    __shared__ unsigned int hsh[K_ * MP_];   // phase 2: 8.2 KB histograms
    __shared__ float xfg[4][K_];
    __shared__ unsigned int sn[256], sf[256];  // phase 3b
    __shared__ float sacc[256];
    __shared__ float xs[4];

    // ================= phase 1: per-instance stats (per-wave LDS atomics) =====
    for (unsigned int u = blockIdx.x; u < US_; u += gridDim.x) {
        if (u == 0 && tid == 0) out[0] = 0.0f;   // later phases atomicAdd
        int b = u >> 8, blk = u & (SBPB_ - 1);
        int pix0 = blk * SCH_;
        if (tid < 192) ws1[tid] = 0.0f;
        __syncthreads();
        float* wacc = ws1 + (tid >> 6) * 48;

        const float* sigp = pred + ((long long)b * 4 + 2) * N_;
        const float* p3p  = pred + ((long long)b * 4 + 3) * N_;
        const int*   insp = inst + (long long)b * N_;
        const int*   labp = lab  + (long long)b * N_;

        float bg = 0.0f;
#pragma unroll
        for (int it = 0; it < SCH_ / (256 * 4); it++) {
            int base = pix0 + (it * 256 + tid) * 4;
            float4 sg = *(const float4*)(sigp + base);
            float4 q3 = *(const float4*)(p3p + base);
            int4 in4 = *(const int4*)(insp + base);
            int4 lb4 = *(const int4*)(labp + base);
            float ss[4] = {sg.x, sg.y, sg.z, sg.w};
            float qq[4] = {q3.x, q3.y, q3.z, q3.w};
            int ii[4] = {in4.x, in4.y, in4.z, in4.w};
            int ll[4] = {lb4.x, lb4.y, lb4.z, lb4.w};
#pragma unroll
            for (int j = 0; j < 4; j++) {
                float seed = fsigmoid_(qq[j]);
                if (ll[j] == 0) bg += seed * seed;
                int ins = ii[j];
                if (ins > 0) {                       // pixel in exactly one instance
                    int pix = base + j;
                    float xm = (float)(pix & (W_ - 1)) * (2.0f / 2047.0f);
                    float ym = (float)(pix >> 10) * (1.0f / 1023.0f);
                    float s = ss[j];
                    int s0 = (ins - 1) * 5;
                    atomicAdd(&wacc[s0], 1.0f);
                    atomicAdd(&wacc[s0 + 1], xm);
                    atomicAdd(&wacc[s0 + 2], ym);
                    atomicAdd(&wacc[s0 + 3], s);
                    atomicAdd(&wacc[s0 + 4], s * s);
                }
            }
        }
#pragma unroll
        for (int off = 32; off; off >>= 1) bg += __shfl_down(bg, off, 64);
        if ((tid & 63) == 0) wacc[40] = bg;
        __syncthreads();
        if (tid < NSTAT)
            pstat[((b * NSTAT + tid) << 8) + blk] =
                ws1[tid] + ws1[48 + tid] + ws1[96 + tid] + ws1[144 + tid];
        __syncthreads();
    }
    gg.sync();

    // ================= phase 2: hist with inline finalize prologue ============
    for (unsigned int u = blockIdx.x; u < UH_; u += gridDim.x) {
        int b = u >> 8, blk = u & (HBPB_ - 1);
        int pix0 = blk * HCH_;

        if (tid < NSTAT * 4) {                        // reduce this image's pstat
            int row = tid >> 2, q = tid & 3;
            const float4* p = (const float4*)(pstat + ((size_t)(b * NSTAT + row) << 8)) + q * 16;
            float4 a = {0, 0, 0, 0};
#pragma unroll
            for (int j = 0; j < 16; j++) {
                float4 v = p[j];
                a.x += v.x; a.y += v.y; a.z += v.z; a.w += v.w;
            }
            sq[row][q] = (a.x + a.y) + (a.z + a.w);
        }
        for (int i = tid; i < K_ * MP_; i += 256) hsh[i] = 0u;
        __syncthreads();
        if (tid < NSTAT) ssum[tid] = (sq[tid][0] + sq[tid][1]) + (sq[tid][2] + sq[tid][3]);
        __syncthreads();
        if (tid < K_) {
            float counts = ssum[tid * 5];
            float cnt = fmaxf(counts, 1.0f);
            float smean = ssum[tid * 5 + 3] / cnt;
            prm[tid][0] = ssum[tid * 5 + 1] / cnt;    // cx
            prm[tid][1] = ssum[tid * 5 + 2] / cnt;    // cy
            prm[tid][2] = expf(10.0f * smean);        // sexp (accurate)
            prm[tid][3] = counts;
            if (blk == 0) {
                svar[tid] = (counts > 0.0f) ? ssum[tid * 5 + 4] / cnt - smean * smean : 0.0f;
                spres[tid] = counts > 0.0f ? 1 : 0;
                wsf[CNT_OFF + b * K_ + tid] = counts;
            }
        }
        __syncthreads();
        if (blk == 0 && tid == 0) {                   // one unit per image
            float np = 0.0f, vl = 0.0f;
#pragma unroll
            for (int k = 0; k < K_; k++) { np += (float)spres[k]; vl += svar[k]; }
            float objf = fmaxf(np, 1.0f);
            wsf[OBJF_OFF + b] = objf;
            atomicAdd(out, (10.0f * vl / objf + ssum[40] / (float)N_) * (1.0f / (float)B_));
        }

        float cx[K_], cy[K_], sxp[K_];
        bool prs[K_];
#pragma unroll
        for (int k = 0; k < K_; k++) {
            cx[k] = prm[k][0]; cy[k] = prm[k][1]; sxp[k] = prm[k][2];
            prs[k] = prm[k][3] > 0.0f;
        }

        const float* p0p = pred + ((long long)b * 4) * N_;
        const float* p1p = p0p + N_;
        const float* p3p = p0p + 3LL * N_;
        const int* insp = inst + (long long)b * N_;

        float sfg[K_];
#pragma unroll
        for (int k = 0; k < K_; k++) sfg[k] = 0.0f;

#pragma unroll
        for (int it = 0; it < HCH_ / (256 * 4); it++) {
            int base = pix0 + (it * 256 + tid) * 4;
            float4 a0 = *(const float4*)(p0p + base);
            float4 a1 = *(const float4*)(p1p + base);
            float4 a3 = *(const float4*)(p3p + base);
            int4 in4 = *(const int4*)(insp + base);
            float v0[4] = {a0.x, a0.y, a0.z, a0.w};
            float v1[4] = {a1.x, a1.y, a1.z, a1.w};
            float v3[4] = {a3.x, a3.y, a3.z, a3.w};
            int ii[4] = {in4.x, in4.y, in4.z, in4.w};
#pragma unroll
            for (int j = 0; j < 4; j++) {
                int pix = base + j;
                float sex = ftanh_(v0[j]) + (float)(pix & (W_ - 1)) * (2.0f / 2047.0f);
                float sey = ftanh_(v1[j]) + (float)(pix >> 10) * (1.0f / 1023.0f);
                float seed = fsigmoid_(v3[j]);
                int ins = ii[j];
#pragma unroll
                for (int k = 0; k < K_; k++) {
                    if (prs[k]) {
                        float dx = sex - cx[k];
                        float dy = sey - cy[k];
                        float dist = __expf(-sxp[k] * (dx * dx + dy * dy));
                        bool fg = (ins == k + 1);
                        int ib = (int)fminf(256.0f * dist, 255.0f);
                        int bin = fg ? 255 - ib : ib;
                        atomicAdd(&hsh[k * MP_ + bin], fg ? 0x10001u : 1u);
                        if (fg) { float d = seed - dist; sfg[k] += d * d; }
                    }
                }
            }
        }
        __syncthreads();

        unsigned int* gp = partial + (size_t)u * KM_;
        for (int i = tid; i < KM_; i += 256)
            gp[i] = hsh[(i >> 8) * MP_ + (i & (M_ - 1))];

#pragma unroll
        for (int k = 0; k < K_; k++) {
            float v = sfg[k];
#pragma unroll
            for (int off = 32; off; off >>= 1) v += __shfl_down(v, off, 64);
            sfg[k] = v;
        }
        if ((tid & 63) == 0) {
            int w = tid >> 6;
#pragma unroll
            for (int k = 0; k < K_; k++) xfg[w][k] = sfg[k];
        }
        __syncthreads();
        if (tid < K_)
            sfgpart[(size_t)(b * K_ + tid) * HBPB_ + blk] =
                xfg[0][tid] + xfg[1][tid] + xfg[2][tid] + xfg[3][tid];
        __syncthreads();
    }
    gg.sync();

    // ============ phase 3a: wide partial reduce (1024 units, full-device BW) ==
    // unit u -> (bk = u>>5, slice = u&31): sum 8 hist-unit partials per bin.
    // per-slice n,f <= 8*2048 = 16384 -> pack (f<<16)|n.
    for (unsigned int u = blockIdx.x; u < BK_ * SLICES_; u += gridDim.x) {
        int bk = u >> 5, s = u & (SLICES_ - 1);
        int b = bk >> 3, k = bk & 7;
        const unsigned int* p = partial + (size_t)(b * HBPB_ + s * PERS_) * KM_ + k * M_ + tid;
        unsigned int n = 0, f = 0;
#pragma unroll
        for (int j = 0; j < PERS_; j++) {
            unsigned int v = p[(size_t)j * KM_];
            n += v & 0xffffu;
            f += v >> 16;
        }
        red[(size_t)u * M_ + tid] = (f << 16) | n;
    }
    gg.sync();

    // ============ phase 3b: Lovasz suffix scan + seed_fg + out add (32 units) =
    // loss = binw*[0.5*J_0 + sum_{j>=1} J_j], J_j = 1-(p-F_j)/(p+R_j-F_j).
    for (unsigned int u = blockIdx.x; u < BK_; u += gridDim.x) {
        int bk = u, b = bk >> 3;
        const unsigned int* rp = red + (size_t)bk * SLICES_ * M_ + tid;
        unsigned int n = 0, f = 0;
#pragma unroll
        for (int s = 0; s < SLICES_; s++) {
            unsigned int v = rp[s * M_];
            n += v & 0xffffu;
            f += v >> 16;
        }
        sn[tid] = n; sf[tid] = f;
        __syncthreads();
#pragma unroll
        for (int s = 1; s < 256; s <<= 1) {           // Hillis-Steele suffix scan
            unsigned int an = sn[tid], af = sf[tid], bn = 0, bf = 0;
            if (tid + s < 256) { bn = sn[tid + s]; bf = sf[tid + s]; }
            __syncthreads();
            sn[tid] = an + bn; sf[tid] = af + bf;
            __syncthreads();
        }
        float pcnt = wsf[CNT_OFF + bk];
        float pp = fmaxf(pcnt, 1.0f);
        unsigned int R = sn[tid], F = sf[tid];
        float J = (R == 0) ? 0.0f : (1.0f - (pp - (float)F) / (pp + (float)(R - F)));
        sacc[tid] = (tid == 0 ? 0.5f : 1.0f) * J;
        __syncthreads();
        for (int s = 128; s > 0; s >>= 1) {
            if (tid < s) sacc[tid] += sacc[tid + s];
            __syncthreads();
        }
        float sv = sfgpart[(size_t)bk * HBPB_ + tid];
#pragma unroll
        for (int off = 32; off; off >>= 1) sv += __shfl_down(sv, off, 64);
        if ((tid & 63) == 0) xs[tid >> 6] = sv;
        __syncthreads();
        if (tid == 0 && pcnt > 0.0f) {
            float lov = sacc[0] * (2.0f / (float)M_);
            float sfgt = (xs[0] + xs[1]) + (xs[2] + xs[3]);
            atomicAdd(out, (lov / wsf[OBJF_OFF + b] + sfgt / (float)N_) * (1.0f / (float)B_));
        }
        __syncthreads();
    }
}

extern "C" void kernel_launch(void* const* d_in, const int* in_sizes, int n_in,
                              void* d_out, int out_size, void* d_ws, size_t ws_size,
                              hipStream_t stream) {
    const float* pred = (const float*)d_in[0];
    const int* inst = (const int*)d_in[1];
    const int* lab = (const int*)d_in[2];
    float* out = (float*)d_out;

    unsigned int* partial = (unsigned int*)d_ws;
    float* sfgpart = (float*)((char*)d_ws + SFG_B);
    float* pstat = (float*)((char*)d_ws + PSTAT_B);
    unsigned int* red = (unsigned int*)((char*)d_ws + RED_B);
    float* wsf = (float*)((char*)d_ws + WSF_B);

    // grid sized to guaranteed co-residency (grid-stride phases keep any
    // grid <= 1024 correct). Occupancy query is a pure host-side lookup —
    // graph-capture safe.
    int nb = 0;
    hipOccupancyMaxActiveBlocksPerMultiprocessor(&nb, fused_kernel, 256, 0);
    if (nb < 1) nb = 1;
    unsigned int grid = (unsigned int)nb * 256u;   // 256 CUs on MI355X
    if (grid > 1024u) grid = 1024u;

    void* args[] = {&pred, &inst, &lab, &pstat, &partial, &sfgpart, &red, &wsf, &out};
    hipLaunchCooperativeKernel((const void*)fused_kernel, dim3(grid), dim3(256),
                               args, 0, stream);
}

// Round 11
// 118.697 us; speedup vs baseline: 2.6648x; 2.6648x over previous
//
#include <hip/hip_runtime.h>
#include <math.h>

namespace {
constexpr int B_ = 4, K_ = 8, W_ = 1024;
constexpr int N_ = 512 * 1024;          // pixels per image
constexpr int M_ = 128;                 // err histogram bins over [0,2]
constexpr int MP_ = M_ + 1;             // padded LDS row
constexpr int BK_ = B_ * K_;
constexpr int KM_ = K_ * M_;            // 1024 bins per hist-block partial

constexpr int HB_ = 1024;               // hist blocks
constexpr int HBPB_ = HB_ / B_;         // 256 per image
constexpr int HCH_ = N_ / HBPB_;        // 2048 pixels per block (2 float4 iters)
constexpr int SB_ = 1024;               // stats blocks
constexpr int SBPB_ = SB_ / B_;         // 256 per image
constexpr int SCH_ = N_ / SBPB_;        // 2048 pixels per block
constexpr int NSTAT = 41;               // interleaved k*5+{cnt,xm,ym,s,s2}, [40]=bg

// workspace layout (bytes)
constexpr size_t PART_BYTES = (size_t)HB_ * KM_ * 4;             // 4 MB
constexpr size_t SFG_OFF_B  = PART_BYTES;                        // 32*256 floats
constexpr size_t PSTAT_OFF_B = SFG_OFF_B + (size_t)BK_ * HBPB_ * 4;
constexpr size_t WSF_OFF_B  = PSTAT_OFF_B + (size_t)B_ * NSTAT * SBPB_ * 4;

// wsf float offsets (written by hist blk==0 blocks, read by lovasz)
constexpr int CNT_OFF  = 0;             // 32 per-(b,k) counts
constexpr int OBJF_OFF = 32;            // 4 per-image objf
}

__device__ __forceinline__ float fsigmoid_(float x) { return 1.0f / (1.0f + __expf(-x)); }
__device__ __forceinline__ float ftanh_(float x) { return 1.0f - 2.0f / (__expf(2.0f * x) + 1.0f); }

// ---- Stage 1: per-instance stats partials; block 0 zeroes out[0] ----
// LAYOUT CONTRACT: pstat row r=b*NSTAT+st holds 256 block-partials at [r<<8 ..].
// st = k*5+{cnt,xm,ym,s,s2}, st=40 = bg seed^2 sum.
// NOTE: no min-waves __launch_bounds__ arg — 41 reg accumulators spill with it (R3).
__global__ __launch_bounds__(256) void stats_kernel(const float* __restrict__ pred,
                                                    const int* __restrict__ inst,
                                                    const int* __restrict__ lab,
                                                    float* __restrict__ pstat,
                                                    float* __restrict__ out) {
    int tid = threadIdx.x;
    if (blockIdx.x == 0 && tid == 0) out[0] = 0.0f;   // later dispatches atomicAdd
    int b = blockIdx.x >> 8;
    int blk = blockIdx.x & (SBPB_ - 1);
    int pix0 = blk * SCH_;

    const float* sigp = pred + ((long long)b * 4 + 2) * N_;
    const float* p3p  = pred + ((long long)b * 4 + 3) * N_;
    const int*   insp = inst + (long long)b * N_;
    const int*   labp = lab  + (long long)b * N_;

    float acc[NSTAT];
#pragma unroll
    for (int i = 0; i < NSTAT; i++) acc[i] = 0.0f;

#pragma unroll
    for (int it = 0; it < SCH_ / (256 * 4); it++) {
        int base = pix0 + (it * 256 + tid) * 4;
        float4 sg = *(const float4*)(sigp + base);
        float4 q3 = *(const float4*)(p3p + base);
        int4 in4 = *(const int4*)(insp + base);
        int4 lb4 = *(const int4*)(labp + base);
        float ss[4] = {sg.x, sg.y, sg.z, sg.w};
        float qq[4] = {q3.x, q3.y, q3.z, q3.w};
        int ii[4] = {in4.x, in4.y, in4.z, in4.w};
        int ll[4] = {lb4.x, lb4.y, lb4.z, lb4.w};
#pragma unroll
        for (int j = 0; j < 4; j++) {
            int pix = base + j;
            float xm = (float)(pix & (W_ - 1)) * (2.0f / 2047.0f);
            float ym = (float)(pix >> 10) * (1.0f / 1023.0f);
            float seed = fsigmoid_(qq[j]);
            if (ll[j] == 0) acc[40] += seed * seed;
            float s = ss[j];
#pragma unroll
            for (int k = 0; k < K_; k++) {
                float m = (ii[j] == k + 1) ? 1.0f : 0.0f;
                acc[k * 5]     += m;
                acc[k * 5 + 1] += m * xm;
                acc[k * 5 + 2] += m * ym;
                acc[k * 5 + 3] += m * s;
                acc[k * 5 + 4] += m * s * s;
            }
        }
    }
#pragma unroll
    for (int i = 0; i < NSTAT; i++) {
        float v = acc[i];
#pragma unroll
        for (int off = 32; off; off >>= 1) v += __shfl_down(v, off, 64);
        acc[i] = v;
    }
    __shared__ float xw[4][NSTAT];
    if ((tid & 63) == 0) {
        int w = tid >> 6;
#pragma unroll
        for (int i = 0; i < NSTAT; i++) xw[w][i] = acc[i];
    }
    __syncthreads();
    if (tid < NSTAT)
        pstat[((b * NSTAT + tid) << 8) + blk] =
            xw[0][tid] + xw[1][tid] + xw[2][tid] + xw[3][tid];
}

// ---- Stage 2: hist with inline finalize prologue ----
// Prologue: every block reduces its image's 41 pstat rows (L2-resident) to get
// cx,cy,sexp,counts. blk==0 blocks additionally write wsf counts/objf and
// atomicAdd the (10*var/objf + bg/N)/B loss terms into out.
__global__ __launch_bounds__(256) void hist_kernel(const float* __restrict__ pred,
                                                   const int* __restrict__ inst,
                                                   const float* __restrict__ pstat,
                                                   float* __restrict__ wsf,
                                                   unsigned int* __restrict__ partial,
                                                   float* __restrict__ sfgpart,
                                                   float* __restrict__ out) {
    __shared__ float sq[NSTAT][4];
    __shared__ float ssum[NSTAT];
    __shared__ float prm[K_][4];        // cx, cy, sexp, counts
    __shared__ float svar[K_];
    __shared__ int spres[K_];
    __shared__ unsigned int hsh[K_ * MP_];   // ~4 KB, 129-padded rows
    __shared__ float xfg[4][K_];

    int tid = threadIdx.x;
    int b = blockIdx.x >> 8;            // HBPB_ = 256 blocks per image
    int blk = blockIdx.x & (HBPB_ - 1);
    int pix0 = blk * HCH_;

    // ---- prologue: reduce pstat rows for this image ----
    if (tid < NSTAT * 4) {
        int row = tid >> 2, q = tid & 3;
        const float4* p = (const float4*)(pstat + ((size_t)(b * NSTAT + row) << 8)) + q * 16;
        float4 a = {0, 0, 0, 0};
#pragma unroll
        for (int j = 0; j < 16; j++) {
            float4 v = p[j];
            a.x += v.x; a.y += v.y; a.z += v.z; a.w += v.w;
        }
        sq[row][q] = (a.x + a.y) + (a.z + a.w);
    }
    for (int i = tid; i < K_ * MP_; i += 256) hsh[i] = 0u;
    __syncthreads();
    if (tid < NSTAT) ssum[tid] = (sq[tid][0] + sq[tid][1]) + (sq[tid][2] + sq[tid][3]);
    __syncthreads();
    if (tid < K_) {
        float counts = ssum[tid * 5];
        float cnt = fmaxf(counts, 1.0f);
        float smean = ssum[tid * 5 + 3] / cnt;
        prm[tid][0] = ssum[tid * 5 + 1] / cnt;        // cx
        prm[tid][1] = ssum[tid * 5 + 2] / cnt;        // cy
        prm[tid][2] = expf(10.0f * smean);            // sexp (accurate)
        prm[tid][3] = counts;
        if (blk == 0) {
            svar[tid] = (counts > 0.0f) ? ssum[tid * 5 + 4] / cnt - smean * smean : 0.0f;
            spres[tid] = counts > 0.0f ? 1 : 0;
            wsf[CNT_OFF + b * K_ + tid] = counts;
        }
    }
    __syncthreads();
    if (blk == 0 && tid == 0) {                       // one block per image
        float np = 0.0f, vl = 0.0f;
#pragma unroll
        for (int k = 0; k < K_; k++) { np += (float)spres[k]; vl += svar[k]; }
        float objf = fmaxf(np, 1.0f);
        wsf[OBJF_OFF + b] = objf;
        atomicAdd(out, (10.0f * vl / objf + ssum[40] / (float)N_) * (1.0f / (float)B_));
    }

    float cx[K_], cy[K_], sxp[K_];
    bool prs[K_];
#pragma unroll
    for (int k = 0; k < K_; k++) {
        cx[k] = prm[k][0]; cy[k] = prm[k][1]; sxp[k] = prm[k][2];
        prs[k] = prm[k][3] > 0.0f;
    }

    const float* p0p = pred + ((long long)b * 4) * N_;
    const float* p1p = p0p + N_;
    const float* p3p = p0p + 3LL * N_;
    const int* insp = inst + (long long)b * N_;

    float sfg[K_];
#pragma unroll
    for (int k = 0; k < K_; k++) sfg[k] = 0.0f;

#pragma unroll
    for (int it = 0; it < HCH_ / (256 * 4); it++) {   // 2 float4 iterations
        int base = pix0 + (it * 256 + tid) * 4;
        float4 a0 = *(const float4*)(p0p + base);
        float4 a1 = *(const float4*)(p1p + base);
        float4 a3 = *(const float4*)(p3p + base);
        int4 in4 = *(const int4*)(insp + base);
        float v0[4] = {a0.x, a0.y, a0.z, a0.w};
        float v1[4] = {a1.x, a1.y, a1.z, a1.w};
        float v3[4] = {a3.x, a3.y, a3.z, a3.w};
        int ii[4] = {in4.x, in4.y, in4.z, in4.w};
#pragma unroll
        for (int j = 0; j < 4; j++) {
            int pix = base + j;
            float sex = ftanh_(v0[j]) + (float)(pix & (W_ - 1)) * (2.0f / 2047.0f);
            float sey = ftanh_(v1[j]) + (float)(pix >> 10) * (1.0f / 1023.0f);
            float seed = fsigmoid_(v3[j]);
            int ins = ii[j];
#pragma unroll
            for (int k = 0; k < K_; k++) {
                if (prs[k]) {
                    float dx = sex - cx[k];
                    float dy = sey - cy[k];
                    float dist = __expf(-sxp[k] * (dx * dx + dy * dy));
                    bool fg = (ins == k + 1);
                    // err_bg=2d, err_fg=2-2d; bin=floor(err*(M/2)) via one cvt:
                    int ib = (int)fminf(128.0f * dist, 127.0f);
                    int bin = fg ? 127 - ib : ib;
                    atomicAdd(&hsh[k * MP_ + bin], fg ? 0x10001u : 1u);
                    if (fg) { float d = seed - dist; sfg[k] += d * d; }
                }
            }
        }
    }
    __syncthreads();

    unsigned int* gp = partial + (size_t)blockIdx.x * KM_;
    for (int i = tid; i < KM_; i += 256)
        gp[i] = hsh[(i >> 7) * MP_ + (i & (M_ - 1))];

    // seed_fg: wave shfl reduce -> cross-wave LDS -> plain store
#pragma unroll
    for (int k = 0; k < K_; k++) {
        float v = sfg[k];
#pragma unroll
        for (int off = 32; off; off >>= 1) v += __shfl_down(v, off, 64);
        sfg[k] = v;
    }
    if ((tid & 63) == 0) {
        int w = tid >> 6;
#pragma unroll
        for (int k = 0; k < K_; k++) xfg[w][k] = sfg[k];
    }
    __syncthreads();
    if (tid < K_)
        sfgpart[(size_t)(b * K_ + tid) * HBPB_ + blk] =
            xfg[0][tid] + xfg[1][tid] + xfg[2][tid] + xfg[3][tid];
}

// ---- Stage 3: fused partial-reduce + Lovasz suffix scan + seed_fg + out add ----
// 32 blocks x 1024 threads: 8 groups x 128 bins; each group sums 32 partials.
// loss = binw*[0.5*J_0 + sum_{j>=1} J_j], J_j = 1-(p-F_j)/(p+R_j-F_j).
__global__ __launch_bounds__(1024) void lovasz_kernel(const unsigned int* __restrict__ partial,
                                                      const float* __restrict__ sfgpart,
                                                      const float* __restrict__ wsf,
                                                      float* __restrict__ out) {
    int bk = blockIdx.x;
    int b = bk >> 3, k = bk & 7;
    int tid = threadIdx.x;
    int bin = tid & (M_ - 1), grp = tid >> 7;   // grp 0..7
    constexpr int PER = HBPB_ / 8;              // 32 partials per group

    const unsigned int* p = partial +
        (size_t)(b * HBPB_ + grp * PER) * KM_ + k * M_ + bin;
    unsigned int n = 0, f = 0;
#pragma unroll 8
    for (int j = 0; j < PER; j++) {             // coalesced: 128 lanes x 4B per j
        unsigned int v = p[(size_t)j * KM_];
        n += v & 0xffffu;
        f += v >> 16;
    }

    __shared__ unsigned int gn[8][M_], gf[8][M_];
    __shared__ unsigned int sn[M_], sf[M_];
    __shared__ float sacc[M_];
    __shared__ float xs[4];
    gn[grp][bin] = n; gf[grp][bin] = f;
    __syncthreads();
    if (grp == 0) {
        unsigned int an = 0, af = 0;
#pragma unroll
        for (int g = 0; g < 8; g++) { an += gn[g][bin]; af += gf[g][bin]; }
        sn[bin] = an; sf[bin] = af;
    }
    __syncthreads();

    // Hillis-Steele inclusive suffix scan over 128 bins (7 steps)
#pragma unroll
    for (int s = 1; s < M_; s <<= 1) {
        unsigned int an = 0, af = 0, bn = 0, bf = 0;
        if (tid < M_) {
            an = sn[tid]; af = sf[tid];
            if (tid + s < M_) { bn = sn[tid + s]; bf = sf[tid + s]; }
        }
        __syncthreads();
        if (tid < M_) { sn[tid] = an + bn; sf[tid] = af + bf; }
        __syncthreads();
    }

    float pcnt = wsf[CNT_OFF + bk];
    float pp = fmaxf(pcnt, 1.0f);
    if (tid < M_) {
        unsigned int R = sn[tid], F = sf[tid];
        float J = (R == 0) ? 0.0f : (1.0f - (pp - (float)F) / (pp + (float)(R - F)));
        sacc[tid] = (tid == 0 ? 0.5f : 1.0f) * J;
    }
    __syncthreads();
    for (int s = M_ / 2; s > 0; s >>= 1) {
        if (tid < s) sacc[tid] += sacc[tid + s];
        __syncthreads();
    }

    // seed_fg total for this (b,k): 256 partials
    float sv = (tid < 256) ? sfgpart[(size_t)bk * HBPB_ + tid] : 0.0f;
#pragma unroll
    for (int off = 32; off; off >>= 1) sv += __shfl_down(sv, off, 64);
    if (tid < 256 && (tid & 63) == 0) xs[tid >> 6] = sv;
    __syncthreads();

    if (tid == 0 && pcnt > 0.0f) {
        float lov = sacc[0] * (2.0f / (float)M_);
        float sfgt = (xs[0] + xs[1]) + (xs[2] + xs[3]);
        float objf = wsf[OBJF_OFF + b];
        atomicAdd(out, (lov / objf + sfgt / (float)N_) * (1.0f / (float)B_));
    }
}

extern "C" void kernel_launch(void* const* d_in, const int* in_sizes, int n_in,
                              void* d_out, int out_size, void* d_ws, size_t ws_size,
                              hipStream_t stream) {
    const float* pred = (const float*)d_in[0];
    const int* inst = (const int*)d_in[1];
    const int* lab = (const int*)d_in[2];
    float* out = (float*)d_out;

    unsigned int* partial = (unsigned int*)d_ws;
    float* sfgpart = (float*)((char*)d_ws + SFG_OFF_B);
    float* pstat = (float*)((char*)d_ws + PSTAT_OFF_B);
    float* wsf = (float*)((char*)d_ws + WSF_OFF_B);

    // 3 dispatches; no memset (stats zeroes out[0]; ws fully overwritten).
    // NOTE: cooperative single-dispatch fusion measured 2.6x WORSE (R10) —
    // grid.sync on gfx950 forces cross-XCD L2 writeback/invalidate (~100us/sync).
    stats_kernel<<<SB_, 256, 0, stream>>>(pred, inst, lab, pstat, out);
    hist_kernel<<<HB_, 256, 0, stream>>>(pred, inst, pstat, wsf, partial, sfgpart, out);
    lovasz_kernel<<<BK_, 1024, 0, stream>>>(partial, sfgpart, wsf, out);
}